// Round 2
// baseline (53764.105 us; speedup 1.0000x reference)
//
#include <hip/hip_runtime.h>
#include <hip/hip_bf16.h>

typedef __hip_bfloat16 bf16;
typedef __attribute__((ext_vector_type(8))) short bf16x8;
typedef __attribute__((ext_vector_type(4))) float f32x4;

#define B_     16
#define N_     1569
#define DIM_   768
#define NHEADS 8
#define HD_    96
#define LK_    393
#define T0_    8
#define H0_    14
#define W0_    14

struct __align__(8) bf16x4s { bf16 a, b, c, d; };

// ----------------------------------------------------- fp32 -> bf16 convert
__global__ __launch_bounds__(256) void cvt_f32_bf16(
    const float* __restrict__ in, bf16* __restrict__ out, int n4) {
  int i = blockIdx.x * 256 + threadIdx.x;
  if (i < n4) {
    float4 v = ((const float4*)in)[i];
    bf16x4s o{__float2bfloat16(v.x), __float2bfloat16(v.y),
              __float2bfloat16(v.z), __float2bfloat16(v.w)};
    ((bf16x4s*)out)[i] = o;
  }
}

// ------------------------------------------- transpose fp32 in -> bf16 out
__global__ __launch_bounds__(256) void transpose_f32_bf16(
    const float* __restrict__ in, bf16* __restrict__ out, int R, int C) {
  __shared__ float tile[32][33];
  int c0 = blockIdx.x * 32, r0 = blockIdx.y * 32;
  int tx = threadIdx.x, ty = threadIdx.y;  // 32 x 8
  for (int i = 0; i < 32; i += 8) {
    int r = r0 + ty + i, c = c0 + tx;
    if (r < R && c < C) tile[ty + i][tx] = in[(size_t)r * C + c];
  }
  __syncthreads();
  for (int i = 0; i < 32; i += 8) {
    int c = c0 + ty + i, r = r0 + tx;
    if (c < C && r < R) out[(size_t)c * R + r] = __float2bfloat16(tile[tx][ty + i]);
  }
}

// ------------------------------------------------------- MFMA GEMM, C=A*BT^T
__device__ __forceinline__ void gl_lds16(const bf16* g, bf16* l) {
  __builtin_amdgcn_global_load_lds(
      (const __attribute__((address_space(1))) void*)g,
      (__attribute__((address_space(3))) void*)l, 16, 0, 0);
}

template <typename OutT>
__global__ __launch_bounds__(256) void gemm_bt(
    const bf16* __restrict__ A, const bf16* __restrict__ BT,
    const float* __restrict__ bias, OutT* __restrict__ C,
    int M, int Nn, int K) {
  constexpr int BM = 128, BN = 128, BK = 32;
  __shared__ __align__(16) bf16 As[BM][BK];
  __shared__ __align__(16) bf16 Bs[BN][BK];
  const int tid = threadIdx.x;
  const int lane = tid & 63, wave = tid >> 6;
  const int bm = blockIdx.x * BM, bn = blockIdx.y * BN;
  const int wm = (wave >> 1) * 64, wn = (wave & 1) * 64;
  const int lrow = lane >> 2;       // 0..15
  const int lcol = (lane & 3) * 8;  // element offset (8 bf16 = 16B)

  f32x4 acc[4][4];
#pragma unroll
  for (int i = 0; i < 4; ++i)
#pragma unroll
    for (int j = 0; j < 4; ++j) acc[i][j] = (f32x4){0.f, 0.f, 0.f, 0.f};

  for (int k0 = 0; k0 < K; k0 += BK) {
#pragma unroll
    for (int r = 0; r < 2; ++r) {
      int arow = bm + wave * 32 + r * 16 + lrow;
      if (arow >= M) arow = M - 1;  // clamp: dup loads, masked at store
      gl_lds16(A + (size_t)arow * K + k0 + lcol, &As[wave * 32 + r * 16][0]);
      int brow = bn + wave * 32 + r * 16 + lrow;  // always < Nn (Nn%128==0)
      gl_lds16(BT + (size_t)brow * K + k0 + lcol, &Bs[wave * 32 + r * 16][0]);
    }
    __syncthreads();
    const int fr = lane & 15, kg = (lane >> 4) * 8;
    bf16x8 af[4], bfr[4];
#pragma unroll
    for (int i = 0; i < 4; ++i) {
      af[i] = *(const bf16x8*)&As[wm + i * 16 + fr][kg];
      bfr[i] = *(const bf16x8*)&Bs[wn + i * 16 + fr][kg];
    }
#pragma unroll
    for (int i = 0; i < 4; ++i)
#pragma unroll
      for (int j = 0; j < 4; ++j)
        acc[i][j] = __builtin_amdgcn_mfma_f32_16x16x32_bf16(af[i], bfr[j],
                                                            acc[i][j], 0, 0, 0);
    __syncthreads();
  }

  const int fr = lane & 15, rg = (lane >> 4) * 4;
#pragma unroll
  for (int j = 0; j < 4; ++j) {
    int col = bn + wn + j * 16 + fr;
    float bv = bias[col];
#pragma unroll
    for (int i = 0; i < 4; ++i) {
#pragma unroll
      for (int r = 0; r < 4; ++r) {
        int row = bm + wm + i * 16 + rg + r;
        if (row < M)
          C[(size_t)row * Nn + col] = (OutT)(acc[i][j][r] + bv);
      }
    }
  }
}

// --------------------------------------------- depthwise 3x3x3 pool + LN
// blockDim (64,4): one wave per output row. which: 0=q,1=k,2=v.
__global__ __launch_bounds__(256) void pool_ln(
    const bf16* __restrict__ qkv, const float* __restrict__ pw,
    const float* __restrict__ g, const float* __restrict__ bt,
    float* __restrict__ outp, int which, int sHW, int oH, int oW, int Lout) {
  const int bh = blockIdx.y;
  const int b = bh >> 3, h = bh & 7;
  const int orow = blockIdx.x * 4 + threadIdx.y;
  if (orow >= Lout) return;
  const int x = threadIdx.x;  // 0..63
  const bf16* base = qkv + (size_t)b * N_ * 2304 + which * 768 + h * 96;
  float v0 = 0.f, v1 = 0.f;
  if (orow == 0) {  // cls token: no pooling
    v0 = (float)base[x];
    if (x < 32) v1 = (float)base[x + 64];
  } else {
    int pos = orow - 1;
    int ot = pos / (oH * oW), r = pos % (oH * oW);
    int oh = r / oW, ow = r % oW;
    for (int kt = 0; kt < 3; ++kt) {
      int it = ot + kt - 1;
      if (it < 0 || it >= T0_) continue;
      for (int kh = 0; kh < 3; ++kh) {
        int ih = oh * sHW + kh - 1;
        if (ih < 0 || ih >= H0_) continue;
        for (int kw = 0; kw < 3; ++kw) {
          int iw = ow * sHW + kw - 1;
          if (iw < 0 || iw >= W0_) continue;
          int n = 1 + (it * H0_ + ih) * W0_ + iw;
          const bf16* ip = base + (size_t)n * 2304;
          int widx = (kt * 3 + kh) * 3 + kw;
          v0 += (float)ip[x] * pw[x * 27 + widx];
          if (x < 32) v1 += (float)ip[x + 64] * pw[(x + 64) * 27 + widx];
        }
      }
    }
  }
  float s = v0 + (x < 32 ? v1 : 0.f);
  float s2 = v0 * v0 + (x < 32 ? v1 * v1 : 0.f);
  for (int off = 32; off > 0; off >>= 1) {
    s += __shfl_down(s, off);
    s2 += __shfl_down(s2, off);
  }
  s = __shfl(s, 0);
  s2 = __shfl(s2, 0);
  float mean = s * (1.f / 96.f);
  float var = s2 * (1.f / 96.f) - mean * mean;
  float rstd = rsqrtf(var + 1e-5f);
  size_t ob = ((size_t)bh * Lout + orow) * 96;
  outp[ob + x] = (v0 - mean) * rstd * g[x] + bt[x];
  if (x < 32)
    outp[ob + x + 64] = (v1 - mean) * rstd * g[x + 64] + bt[x + 64];
}

// ----------------------------------------------------------- fused attention
// grid (99, 128): 16 q rows per block for one (b,h). 256 threads.
__global__ __launch_bounds__(256) void attn_fused(
    const float* __restrict__ qp, const float* __restrict__ kp,
    const float* __restrict__ vp, const float* __restrict__ rph,
    const float* __restrict__ rpw, const float* __restrict__ rpt,
    bf16* __restrict__ aout) {
  __shared__ __align__(16) float qs[16][100];  // pad: breaks 96%32==0 aliasing
  __shared__ __align__(16) float ks[64][100];  // k tile, reused for v tile
  __shared__ float S[16][400];                 // logits -> probs
  __shared__ float relb[16][24];               // relt[0..7] relh[8..14] relw[16..22]
  __shared__ float red[16][16];

  const int tid = threadIdx.x;
  const int bh = blockIdx.y;
  const int b = bh >> 3, h = bh & 7;
  const int q0 = blockIdx.x * 16;
  const float* qb = qp + (size_t)bh * N_ * HD_;
  const float* kb = kp + (size_t)bh * LK_ * HD_;
  const float* vb = vp + (size_t)bh * LK_ * HD_;

  for (int i = tid; i < 16 * HD_; i += 256) {
    int qi = i / HD_, d = i % HD_;
    int p = q0 + qi;
    if (p >= N_) p = N_ - 1;
    qs[qi][d] = qb[(size_t)p * HD_ + d];
  }
  __syncthreads();

  // 22 rel-pos dots per q row (kt 0..7, kh 0..6, kw 0..6)
  for (int t = tid; t < 16 * 22; t += 256) {
    int qi = t / 22, j = t % 22;
    int p = q0 + qi;
    if (p >= 1 && p < N_) {
      int pos = p - 1;
      int qt = pos / 196, rr = pos % 196;
      int qh = rr / 14, qw = rr % 14;
      const float* tab;
      int slot;
      if (j < 8) {
        tab = rpt + (size_t)(qt - j + 7) * HD_;          // Rt idx = qt-kt+7
        slot = j;
      } else if (j < 15) {
        int kh = j - 8;
        tab = rph + (size_t)(qh - 2 * kh + 12) * HD_;    // Rh idx = qh-2kh+12
        slot = j;
      } else {
        int kw = j - 15;
        tab = rpw + (size_t)(qw - 2 * kw + 12) * HD_;    // Rw idx = qw-2kw+12
        slot = 16 + kw;
      }
      float acc = 0.f;
      for (int d = 0; d < HD_; ++d) acc += qs[qi][d] * tab[d];
      relb[qi][slot] = acc;
    }
  }
  __syncthreads();

  const int qi = tid >> 4, lj = tid & 15;
  const int p = q0 + qi;
  const float scale = 0.102062072615966f;  // 96^-0.5

  // ---- logits ----
  for (int t = 0; t < 7; ++t) {
    for (int i = tid; i < 64 * HD_; i += 256) {
      int kk = i / HD_, d = i % HD_;
      int key = t * 64 + kk;
      if (key >= LK_) key = LK_ - 1;
      ks[kk][d] = kb[(size_t)key * HD_ + d];
    }
    __syncthreads();
    for (int rr = 0; rr < 4; ++rr) {
      int kl = lj + 16 * rr;
      int key = t * 64 + kl;
      float acc = 0.f;
      const float4* qv4 = (const float4*)&qs[qi][0];
      const float4* kv4 = (const float4*)&ks[kl][0];
#pragma unroll
      for (int d4 = 0; d4 < 24; ++d4) {
        float4 a = qv4[d4], c = kv4[d4];
        acc += a.x * c.x + a.y * c.y + a.z * c.z + a.w * c.w;
      }
      if (key < LK_) {
        float logit = acc * scale;
        if (p >= 1 && p < N_ && key >= 1) {
          int km = key - 1;
          int kt = km / 49, r2 = km % 49;
          logit += relb[qi][kt] + relb[qi][8 + r2 / 7] + relb[qi][16 + r2 % 7];
        }
        S[qi][key] = logit;
      }
    }
    __syncthreads();
  }

  // ---- softmax over 393 (16 threads per row) ----
  float mx = -1e30f;
  for (int key = lj; key < LK_; key += 16) mx = fmaxf(mx, S[qi][key]);
  red[qi][lj] = mx;
  __syncthreads();
#pragma unroll
  for (int i = 0; i < 16; ++i) mx = fmaxf(mx, red[qi][i]);
  float sum = 0.f;
  for (int key = lj; key < LK_; key += 16) {
    float e = __expf(S[qi][key] - mx);
    S[qi][key] = e;
    sum += e;
  }
  __syncthreads();
  red[qi][lj] = sum;
  __syncthreads();
  sum = 0.f;
#pragma unroll
  for (int i = 0; i < 16; ++i) sum += red[qi][i];
  const float inv = 1.f / sum;

  // ---- PV (thread (qi, lj) owns dims lj+16c) ----
  float out[6] = {0.f, 0.f, 0.f, 0.f, 0.f, 0.f};
  for (int t = 0; t < 7; ++t) {
    __syncthreads();  // WAR on ks
    for (int i = tid; i < 64 * HD_; i += 256) {
      int kk = i / HD_, d = i % HD_;
      int key = t * 64 + kk;
      ks[kk][d] = (key < LK_) ? vb[(size_t)key * HD_ + d] : 0.f;
    }
    __syncthreads();
    int kmax = LK_ - t * 64;
    if (kmax > 64) kmax = 64;
    for (int k = 0; k < kmax; ++k) {
      float pk = S[qi][t * 64 + k];
#pragma unroll
      for (int c = 0; c < 6; ++c) out[c] += pk * ks[k][lj + 16 * c];
    }
  }

  if (p < N_) {
#pragma unroll
    for (int c = 0; c < 6; ++c) {
      int d = lj + 16 * c;
      float val = out[c] * inv;
      if (p >= 1) val += qs[qi][d];  // residual: pooled-LN q, body rows only
      aout[((size_t)b * N_ + p) * DIM_ + h * HD_ + d] = __float2bfloat16(val);
    }
  }
}

// ------------------------------------------------------------------- launch
extern "C" void kernel_launch(void* const* d_in, const int* in_sizes, int n_in,
                              void* d_out, int out_size, void* d_ws,
                              size_t ws_size, hipStream_t stream) {
  (void)in_sizes; (void)n_in; (void)out_size; (void)ws_size;
  const float* x      = (const float*)d_in[0];
  const float* qkv_w  = (const float*)d_in[1];
  const float* qkv_b  = (const float*)d_in[2];
  const float* pool_q = (const float*)d_in[3];
  const float* pool_k = (const float*)d_in[4];
  const float* pool_v = (const float*)d_in[5];
  const float* ln_q_g = (const float*)d_in[6];
  const float* ln_q_b = (const float*)d_in[7];
  const float* ln_k_g = (const float*)d_in[8];
  const float* ln_k_b = (const float*)d_in[9];
  const float* ln_v_g = (const float*)d_in[10];
  const float* ln_v_b = (const float*)d_in[11];
  const float* rph    = (const float*)d_in[12];
  const float* rpw    = (const float*)d_in[13];
  const float* rpt    = (const float*)d_in[14];
  const float* proj_w = (const float*)d_in[15];
  const float* proj_b = (const float*)d_in[16];

  char* ws = (char*)d_ws;
  bf16* wt_qkv  = (bf16*)(ws);                  // 2304x768 bf16   (3.54 MB)
  bf16* wt_proj = (bf16*)(ws + 3538944);        // 768x768 bf16    (1.18 MB)
  bf16* xb      = (bf16*)(ws + 4718592);        // 25104x768 bf16  (38.6 MB)
  bf16* aout    = xb;                           // reuse: xb dead after gemm#1
  bf16* qkv     = (bf16*)(ws + 43278336);       // 25104x2304 bf16 (115.7 MB)
  float* qpool  = (float*)(ws + 158957568);     // 128x1569x96 f32 (77.1 MB)
  float* kpool  = (float*)(ws + 236077056);     // 128x393x96 f32  (19.3 MB)
  float* vpool  = (float*)(ws + 255393792);     // 128x393x96 f32  (19.3 MB)
  float* outp   = (float*)d_out;                // fp32 output per reference

  int n4 = (B_ * N_ * DIM_) / 4;
  cvt_f32_bf16<<<(n4 + 255) / 256, 256, 0, stream>>>(x, xb, n4);
  transpose_f32_bf16<<<dim3(72, 24), dim3(32, 8), 0, stream>>>(qkv_w, wt_qkv, 768, 2304);
  transpose_f32_bf16<<<dim3(24, 24), dim3(32, 8), 0, stream>>>(proj_w, wt_proj, 768, 768);

  gemm_bt<bf16><<<dim3(197, 18), 256, 0, stream>>>(xb, wt_qkv, qkv_b, qkv,
                                                   B_ * N_, 3 * DIM_, DIM_);

  dim3 pb(64, 4);
  pool_ln<<<dim3(393, 128), pb, 0, stream>>>(qkv, pool_q, ln_q_g, ln_q_b, qpool,
                                             0, 1, 14, 14, N_);
  pool_ln<<<dim3(99, 128), pb, 0, stream>>>(qkv, pool_k, ln_k_g, ln_k_b, kpool,
                                            1, 2, 7, 7, LK_);
  pool_ln<<<dim3(99, 128), pb, 0, stream>>>(qkv, pool_v, ln_v_g, ln_v_b, vpool,
                                            2, 2, 7, 7, LK_);

  attn_fused<<<dim3(99, 128), 256, 0, stream>>>(qpool, kpool, vpool, rph, rpw,
                                                rpt, aout);

  gemm_bt<float><<<dim3(197, 6), 256, 0, stream>>>(aout, wt_proj, proj_b, outp,
                                                   B_ * N_, DIM_, DIM_);
}

// Round 3
// 1556.334 us; speedup vs baseline: 34.5453x; 34.5453x over previous
//
#include <hip/hip_runtime.h>
#include <hip/hip_bf16.h>

typedef __hip_bfloat16 bf16;
typedef __attribute__((ext_vector_type(8))) short bf16x8;
typedef __attribute__((ext_vector_type(4))) float f32x4;

#define B_     16
#define N_     1569
#define DIM_   768
#define NHEADS 8
#define HD_    96
#define LK_    393
#define T0_    8
#define H0_    14
#define W0_    14

struct __align__(8) bf16x4s { bf16 a, b, c, d; };

// ----------------------------------------------------- fp32 -> bf16 convert
__global__ __launch_bounds__(256) void cvt_f32_bf16(
    const float* __restrict__ in, bf16* __restrict__ out, int n4) {
  int i = blockIdx.x * 256 + threadIdx.x;
  if (i < n4) {
    float4 v = ((const float4*)in)[i];
    bf16x4s o{__float2bfloat16(v.x), __float2bfloat16(v.y),
              __float2bfloat16(v.z), __float2bfloat16(v.w)};
    ((bf16x4s*)out)[i] = o;
  }
}

// ------------------------------------------- transpose fp32 in -> bf16 out
__global__ __launch_bounds__(256) void transpose_f32_bf16(
    const float* __restrict__ in, bf16* __restrict__ out, int R, int C) {
  __shared__ float tile[32][33];
  int c0 = blockIdx.x * 32, r0 = blockIdx.y * 32;
  int tx = threadIdx.x, ty = threadIdx.y;  // 32 x 8
  for (int i = 0; i < 32; i += 8) {
    int r = r0 + ty + i, c = c0 + tx;
    if (r < R && c < C) tile[ty + i][tx] = in[(size_t)r * C + c];
  }
  __syncthreads();
  for (int i = 0; i < 32; i += 8) {
    int c = c0 + ty + i, r = r0 + tx;
    if (c < C && r < R) out[(size_t)c * R + r] = __float2bfloat16(tile[tx][ty + i]);
  }
}

// ------------------------------------------------------- MFMA GEMM, C=A*BT^T
__device__ __forceinline__ void gl_lds16(const bf16* g, bf16* l) {
  __builtin_amdgcn_global_load_lds(
      (const __attribute__((address_space(1))) void*)g,
      (__attribute__((address_space(3))) void*)l, 16, 0, 0);
}

template <typename OutT>
__global__ __launch_bounds__(256) void gemm_bt(
    const bf16* __restrict__ A, const bf16* __restrict__ BT,
    const float* __restrict__ bias, OutT* __restrict__ C,
    int M, int Nn, int K) {
  constexpr int BM = 128, BN = 128, BK = 32;
  __shared__ __align__(16) bf16 As[BM][BK];
  __shared__ __align__(16) bf16 Bs[BN][BK];
  const int tid = threadIdx.x;
  const int lane = tid & 63, wave = tid >> 6;
  const int bm = blockIdx.x * BM, bn = blockIdx.y * BN;
  const int wm = (wave >> 1) * 64, wn = (wave & 1) * 64;
  const int lrow = lane >> 2;       // 0..15
  const int lcol = (lane & 3) * 8;  // element offset (8 bf16 = 16B)

  f32x4 acc[4][4];
#pragma unroll
  for (int i = 0; i < 4; ++i)
#pragma unroll
    for (int j = 0; j < 4; ++j) acc[i][j] = (f32x4){0.f, 0.f, 0.f, 0.f};

  for (int k0 = 0; k0 < K; k0 += BK) {
#pragma unroll
    for (int r = 0; r < 2; ++r) {
      int arow = bm + wave * 32 + r * 16 + lrow;
      if (arow >= M) arow = M - 1;  // clamp: dup loads, masked at store
      gl_lds16(A + (size_t)arow * K + k0 + lcol, &As[wave * 32 + r * 16][0]);
      int brow = bn + wave * 32 + r * 16 + lrow;  // always < Nn (Nn%128==0)
      gl_lds16(BT + (size_t)brow * K + k0 + lcol, &Bs[wave * 32 + r * 16][0]);
    }
    __syncthreads();
    const int fr = lane & 15, kg = (lane >> 4) * 8;
    bf16x8 af[4], bfr[4];
#pragma unroll
    for (int i = 0; i < 4; ++i) {
      af[i] = *(const bf16x8*)&As[wm + i * 16 + fr][kg];
      bfr[i] = *(const bf16x8*)&Bs[wn + i * 16 + fr][kg];
    }
#pragma unroll
    for (int i = 0; i < 4; ++i)
#pragma unroll
      for (int j = 0; j < 4; ++j)
        acc[i][j] = __builtin_amdgcn_mfma_f32_16x16x32_bf16(af[i], bfr[j],
                                                            acc[i][j], 0, 0, 0);
    __syncthreads();
  }

  const int fr = lane & 15, rg = (lane >> 4) * 4;
#pragma unroll
  for (int j = 0; j < 4; ++j) {
    int col = bn + wn + j * 16 + fr;
    float bv = bias[col];
#pragma unroll
    for (int i = 0; i < 4; ++i) {
#pragma unroll
      for (int r = 0; r < 4; ++r) {
        int row = bm + wm + i * 16 + rg + r;
        if (row < M)
          C[(size_t)row * Nn + col] = (OutT)(acc[i][j][r] + bv);
      }
    }
  }
}

// --------------------------------------------- depthwise 3x3x3 pool + LN
// blockDim (64,4): one wave per output row. which: 0=q,1=k,2=v. bf16 out.
__global__ __launch_bounds__(256) void pool_ln(
    const bf16* __restrict__ qkv, const float* __restrict__ pw,
    const float* __restrict__ g, const float* __restrict__ bt,
    bf16* __restrict__ outp, int which, int sHW, int oH, int oW, int Lout) {
  const int bh = blockIdx.y;
  const int b = bh >> 3, h = bh & 7;
  const int orow = blockIdx.x * 4 + threadIdx.y;
  if (orow >= Lout) return;
  const int x = threadIdx.x;  // 0..63
  const bf16* base = qkv + (size_t)b * N_ * 2304 + which * 768 + h * 96;
  float v0 = 0.f, v1 = 0.f;
  if (orow == 0) {  // cls token: no pooling
    v0 = (float)base[x];
    if (x < 32) v1 = (float)base[x + 64];
  } else {
    int pos = orow - 1;
    int ot = pos / (oH * oW), r = pos % (oH * oW);
    int oh = r / oW, ow = r % oW;
    for (int kt = 0; kt < 3; ++kt) {
      int it = ot + kt - 1;
      if (it < 0 || it >= T0_) continue;
      for (int kh = 0; kh < 3; ++kh) {
        int ih = oh * sHW + kh - 1;
        if (ih < 0 || ih >= H0_) continue;
        for (int kw = 0; kw < 3; ++kw) {
          int iw = ow * sHW + kw - 1;
          if (iw < 0 || iw >= W0_) continue;
          int n = 1 + (it * H0_ + ih) * W0_ + iw;
          const bf16* ip = base + (size_t)n * 2304;
          int widx = (kt * 3 + kh) * 3 + kw;
          v0 += (float)ip[x] * pw[x * 27 + widx];
          if (x < 32) v1 += (float)ip[x + 64] * pw[(x + 64) * 27 + widx];
        }
      }
    }
  }
  float s = v0 + (x < 32 ? v1 : 0.f);
  float s2 = v0 * v0 + (x < 32 ? v1 * v1 : 0.f);
  for (int off = 32; off > 0; off >>= 1) {
    s += __shfl_down(s, off);
    s2 += __shfl_down(s2, off);
  }
  s = __shfl(s, 0);
  s2 = __shfl(s2, 0);
  float mean = s * (1.f / 96.f);
  float var = s2 * (1.f / 96.f) - mean * mean;
  float rstd = rsqrtf(var + 1e-5f);
  size_t ob = ((size_t)bh * Lout + orow) * 96;
  outp[ob + x] = __float2bfloat16((v0 - mean) * rstd * g[x] + bt[x]);
  if (x < 32)
    outp[ob + x + 64] =
        __float2bfloat16((v1 - mean) * rstd * g[x + 64] + bt[x + 64]);
}

// ------------------------------------------------- MFMA flash attention
// grid (25, 128): 64 q rows per block, one (b,h) per blockIdx.y. 256 thr.
__global__ __launch_bounds__(256) void attn_fused(
    const bf16* __restrict__ qp, const bf16* __restrict__ kp,
    const bf16* __restrict__ vp, const float* __restrict__ rph,
    const float* __restrict__ rpw, const float* __restrict__ rpt,
    bf16* __restrict__ aout) {
  __shared__ __align__(16) bf16 Qs[64][104];   // pad 96->104 (16B-aligned rows)
  __shared__ __align__(16) bf16 Ks[64][104];
  __shared__ __align__(16) bf16 Vt[96][72];    // V transposed [d][key]
  __shared__ __align__(16) bf16 Ps[4][16][72]; // per-wave P tile
  __shared__ float relb[64][24];               // t:0..7 h:8..14 w:16..22

  const int tid = threadIdx.x;
  const int wv = tid >> 6, lane = tid & 63;
  const int col = lane & 15, quad = lane >> 4;
  const int bh = blockIdx.y;
  const int b = bh >> 3, h = bh & 7;
  const int q0 = blockIdx.x * 64;
  const bf16* qb = qp + (size_t)bh * N_ * HD_;
  const bf16* kb = kp + (size_t)bh * LK_ * HD_;
  const bf16* vb = vp + (size_t)bh * LK_ * HD_;
  const float scale = 0.102062072615966f;  // 96^-0.5

  // ---- stage Q tile (64 x 96) ----
  for (int c = tid; c < 768; c += 256) {  // 768 chunks of 8 elems
    int row = c / 12, seg = c % 12;
    int p = q0 + row;
    if (p >= N_) p = N_ - 1;
    uint4 v = *(const uint4*)(qb + (size_t)p * HD_ + seg * 8);
    *(uint4*)&Qs[row][seg * 8] = v;
  }
  __syncthreads();

  // ---- rel-pos dot tables: 22 per q row ----
  for (int t = tid; t < 64 * 22; t += 256) {
    int qr = t / 22, j = t % 22;
    int p = q0 + qr;
    if (p >= 1 && p < N_) {
      int pos = p - 1;
      int qt = pos / 196, rr = pos % 196;
      int qh = rr / 14, qw = rr % 14;
      const float* tab;
      int slot;
      if (j < 8) { tab = rpt + (size_t)(qt - j + 7) * HD_; slot = j; }
      else if (j < 15) { int kh = j - 8; tab = rph + (size_t)(qh - 2 * kh + 12) * HD_; slot = j; }
      else { int kw = j - 15; tab = rpw + (size_t)(qw - 2 * kw + 12) * HD_; slot = 16 + kw; }
      float acc = 0.f;
      for (int d = 0; d < HD_; ++d) acc += (float)Qs[qr][d] * tab[d];
      relb[qr][slot] = acc;
    }
  }

  // ---- flash state (4 q rows per lane: row = wv*16 + quad*4 + r) ----
  float mrun[4] = {-1e30f, -1e30f, -1e30f, -1e30f};
  float lrun[4] = {0.f, 0.f, 0.f, 0.f};
  f32x4 oacc[6];
#pragma unroll
  for (int dt = 0; dt < 6; ++dt) oacc[dt] = (f32x4){0.f, 0.f, 0.f, 0.f};

  for (int kt_i = 0; kt_i < 7; ++kt_i) {
    const int kt0 = kt_i * 64;
    __syncthreads();  // prior reads of Ks/Vt done; relb visible (iter 0)
    // ---- stage K (64x96) and V^T (96x64) ----
    for (int c = tid; c < 768; c += 256) {
      int row = c / 12, seg = c % 12;
      int key = kt0 + row;
      if (key >= LK_) key = LK_ - 1;
      uint4 v = *(const uint4*)(kb + (size_t)key * HD_ + seg * 8);
      *(uint4*)&Ks[row][seg * 8] = v;
      union { uint4 u; bf16 e[8]; } tv;
      tv.u = *(const uint4*)(vb + (size_t)key * HD_ + seg * 8);
#pragma unroll
      for (int j = 0; j < 8; ++j) Vt[seg * 8 + j][row] = tv.e[j];
    }
    __syncthreads();

    // ---- S = Q K^T : wave wv computes rows [wv*16, wv*16+16) x 64 keys ----
    f32x4 sacc[4];
#pragma unroll
    for (int jt = 0; jt < 4; ++jt) sacc[jt] = (f32x4){0.f, 0.f, 0.f, 0.f};
#pragma unroll
    for (int ks_ = 0; ks_ < 3; ++ks_) {
      bf16x8 aq = *(const bf16x8*)&Qs[wv * 16 + col][ks_ * 32 + quad * 8];
#pragma unroll
      for (int jt = 0; jt < 4; ++jt) {
        bf16x8 bk = *(const bf16x8*)&Ks[jt * 16 + col][ks_ * 32 + quad * 8];
        sacc[jt] = __builtin_amdgcn_mfma_f32_16x16x32_bf16(aq, bk, sacc[jt], 0, 0, 0);
      }
    }

    // ---- scale + rel-pos bias + validity ----
    float sv[4][4];  // [jt][reg]
#pragma unroll
    for (int jt = 0; jt < 4; ++jt) {
      int kglob = kt0 + jt * 16 + col;
      bool kvalid = (kglob < LK_);
      int kbod = (kglob >= 1) ? kglob - 1 : 0;
      int kt_ = kbod / 49, krem = kbod % 49;
      int kh_ = krem / 7, kw_ = krem % 7;
#pragma unroll
      for (int r = 0; r < 4; ++r) {
        int qr = wv * 16 + quad * 4 + r;
        int p = q0 + qr;
        float s = sacc[jt][r] * scale;
        if (kvalid && kglob >= 1 && p >= 1 && p < N_)
          s += relb[qr][kt_] + relb[qr][8 + kh_] + relb[qr][16 + kw_];
        if (!kvalid) s = -1e30f;
        sv[jt][r] = s;
      }
    }

    // ---- online softmax (row spread over 16-lane cluster) ----
    float pexp[4][4];
#pragma unroll
    for (int r = 0; r < 4; ++r) {
      float pm = fmaxf(fmaxf(sv[0][r], sv[1][r]), fmaxf(sv[2][r], sv[3][r]));
#pragma unroll
      for (int mk = 1; mk < 16; mk <<= 1) pm = fmaxf(pm, __shfl_xor(pm, mk));
      float mn = fmaxf(mrun[r], pm);
      float alpha = __expf(mrun[r] - mn);
      mrun[r] = mn;
      float rs = 0.f;
#pragma unroll
      for (int jt = 0; jt < 4; ++jt) {
        float e = __expf(sv[jt][r] - mn);
        pexp[jt][r] = e;
        rs += e;
      }
#pragma unroll
      for (int mk = 1; mk < 16; mk <<= 1) rs += __shfl_xor(rs, mk);
      lrun[r] = lrun[r] * alpha + rs;
#pragma unroll
      for (int dt = 0; dt < 6; ++dt) {
        oacc[dt][r] *= alpha;
      }
    }

    // ---- P (C-layout) -> LDS -> A-layout ----
#pragma unroll
    for (int jt = 0; jt < 4; ++jt)
#pragma unroll
      for (int r = 0; r < 4; ++r)
        Ps[wv][quad * 4 + r][jt * 16 + col] = __float2bfloat16(pexp[jt][r]);
    // wave-private LDS region: compiler's lgkmcnt wait orders write->read

    // ---- O += P V ----
#pragma unroll
    for (int ks_ = 0; ks_ < 2; ++ks_) {
      bf16x8 ap = *(const bf16x8*)&Ps[wv][col][ks_ * 32 + quad * 8];
#pragma unroll
      for (int dt = 0; dt < 6; ++dt) {
        bf16x8 bv = *(const bf16x8*)&Vt[dt * 16 + col][ks_ * 32 + quad * 8];
        oacc[dt] = __builtin_amdgcn_mfma_f32_16x16x32_bf16(ap, bv, oacc[dt], 0, 0, 0);
      }
    }
  }

  // ---- epilogue: O/l + residual q, store bf16 ----
#pragma unroll
  for (int r = 0; r < 4; ++r) {
    int qr = wv * 16 + quad * 4 + r;
    int p = q0 + qr;
    if (p >= N_) continue;
    float inv = 1.f / lrun[r];
#pragma unroll
    for (int dt = 0; dt < 6; ++dt) {
      int d = dt * 16 + col;
      float val = oacc[dt][r] * inv;
      if (p >= 1) val += (float)Qs[qr][d];
      aout[((size_t)b * N_ + p) * DIM_ + h * HD_ + d] = __float2bfloat16(val);
    }
  }
}

// ------------------------------------------------------------------- launch
extern "C" void kernel_launch(void* const* d_in, const int* in_sizes, int n_in,
                              void* d_out, int out_size, void* d_ws,
                              size_t ws_size, hipStream_t stream) {
  (void)in_sizes; (void)n_in; (void)out_size; (void)ws_size;
  const float* x      = (const float*)d_in[0];
  const float* qkv_w  = (const float*)d_in[1];
  const float* qkv_b  = (const float*)d_in[2];
  const float* pool_q = (const float*)d_in[3];
  const float* pool_k = (const float*)d_in[4];
  const float* pool_v = (const float*)d_in[5];
  const float* ln_q_g = (const float*)d_in[6];
  const float* ln_q_b = (const float*)d_in[7];
  const float* ln_k_g = (const float*)d_in[8];
  const float* ln_k_b = (const float*)d_in[9];
  const float* ln_v_g = (const float*)d_in[10];
  const float* ln_v_b = (const float*)d_in[11];
  const float* rph    = (const float*)d_in[12];
  const float* rpw    = (const float*)d_in[13];
  const float* rpt    = (const float*)d_in[14];
  const float* proj_w = (const float*)d_in[15];
  const float* proj_b = (const float*)d_in[16];

  char* ws = (char*)d_ws;
  bf16* wt_qkv  = (bf16*)(ws);                  // 2304x768 bf16   (3.54 MB)
  bf16* wt_proj = (bf16*)(ws + 3538944);        // 768x768 bf16    (1.18 MB)
  bf16* xb      = (bf16*)(ws + 4718592);        // 25104x768 bf16  (38.6 MB)
  bf16* aout    = xb;                           // reuse: xb dead after gemm#1
  bf16* qkv     = (bf16*)(ws + 43278336);       // 25104x2304 bf16 (115.7 MB)
  bf16* qpoolb  = (bf16*)(ws + 158957568);      // 128x1569x96 bf16 (38.6 MB)
  bf16* kpoolb  = (bf16*)(ws + 197517312);      // 128x393x96 bf16  (9.7 MB)
  bf16* vpoolb  = (bf16*)(ws + 207175680);      // 128x393x96 bf16  (9.7 MB)
  float* outp   = (float*)d_out;                // fp32 output per reference

  int n4 = (B_ * N_ * DIM_) / 4;
  cvt_f32_bf16<<<(n4 + 255) / 256, 256, 0, stream>>>(x, xb, n4);
  transpose_f32_bf16<<<dim3(72, 24), dim3(32, 8), 0, stream>>>(qkv_w, wt_qkv, 768, 2304);
  transpose_f32_bf16<<<dim3(24, 24), dim3(32, 8), 0, stream>>>(proj_w, wt_proj, 768, 768);

  gemm_bt<bf16><<<dim3(197, 18), 256, 0, stream>>>(xb, wt_qkv, qkv_b, qkv,
                                                   B_ * N_, 3 * DIM_, DIM_);

  dim3 pb(64, 4);
  pool_ln<<<dim3(393, 128), pb, 0, stream>>>(qkv, pool_q, ln_q_g, ln_q_b, qpoolb,
                                             0, 1, 14, 14, N_);
  pool_ln<<<dim3(99, 128), pb, 0, stream>>>(qkv, pool_k, ln_k_g, ln_k_b, kpoolb,
                                            1, 2, 7, 7, LK_);
  pool_ln<<<dim3(99, 128), pb, 0, stream>>>(qkv, pool_v, ln_v_g, ln_v_b, vpoolb,
                                            2, 2, 7, 7, LK_);

  attn_fused<<<dim3(25, 128), 256, 0, stream>>>(qpoolb, kpoolb, vpoolb, rph,
                                                rpw, rpt, aout);

  gemm_bt<float><<<dim3(197, 6), 256, 0, stream>>>(aout, wt_proj, proj_b, outp,
                                                   B_ * N_, DIM_, DIM_);
}

// Round 4
// 1444.954 us; speedup vs baseline: 37.2082x; 1.0771x over previous
//
#include <hip/hip_runtime.h>
#include <hip/hip_bf16.h>

typedef __hip_bfloat16 bf16;
typedef __attribute__((ext_vector_type(8))) short bf16x8;
typedef __attribute__((ext_vector_type(4))) float f32x4;

#define B_     16
#define N_     1569
#define DIM_   768
#define NHEADS 8
#define HD_    96
#define LK_    393
#define T0_    8
#define H0_    14
#define W0_    14

struct __align__(8) bf16x4s { bf16 a, b, c, d; };

// ----------------------------------------------------- fp32 -> bf16 convert
__global__ __launch_bounds__(256) void cvt_f32_bf16(
    const float* __restrict__ in, bf16* __restrict__ out, int n4) {
  int i = blockIdx.x * 256 + threadIdx.x;
  if (i < n4) {
    float4 v = ((const float4*)in)[i];
    bf16x4s o{__float2bfloat16(v.x), __float2bfloat16(v.y),
              __float2bfloat16(v.z), __float2bfloat16(v.w)};
    ((bf16x4s*)out)[i] = o;
  }
}

// ------------------------------------------- transpose fp32 in -> bf16 out
__global__ __launch_bounds__(256) void transpose_f32_bf16(
    const float* __restrict__ in, bf16* __restrict__ out, int R, int C) {
  __shared__ float tile[32][33];
  int c0 = blockIdx.x * 32, r0 = blockIdx.y * 32;
  int tx = threadIdx.x, ty = threadIdx.y;  // 32 x 8
  for (int i = 0; i < 32; i += 8) {
    int r = r0 + ty + i, c = c0 + tx;
    if (r < R && c < C) tile[ty + i][tx] = in[(size_t)r * C + c];
  }
  __syncthreads();
  for (int i = 0; i < 32; i += 8) {
    int c = c0 + ty + i, r = r0 + tx;
    if (c < C && r < R) out[(size_t)c * R + r] = __float2bfloat16(tile[tx][ty + i]);
  }
}

// --------------------------- pool-weight transpose: [96][27] -> [27][96] x3
__global__ __launch_bounds__(256) void prep_pw(
    const float* __restrict__ wq, const float* __restrict__ wk,
    const float* __restrict__ wv, float* __restrict__ outp) {
  int i = blockIdx.x * 256 + threadIdx.x;
  if (i < 2592) {
    int widx = i / 96, x = i % 96;
    outp[i]        = wq[x * 27 + widx];
    outp[2592 + i] = wk[x * 27 + widx];
    outp[5184 + i] = wv[x * 27 + widx];
  }
}

// ------------------------------------------------------- MFMA GEMM, C=A*BT^T
__device__ __forceinline__ void gl_lds16(const bf16* g, bf16* l) {
  __builtin_amdgcn_global_load_lds(
      (const __attribute__((address_space(1))) void*)g,
      (__attribute__((address_space(3))) void*)l, 16, 0, 0);
}

template <typename OutT>
__global__ __launch_bounds__(256) void gemm_bt(
    const bf16* __restrict__ A, const bf16* __restrict__ BT,
    const float* __restrict__ bias, OutT* __restrict__ C,
    int M, int Nn, int K) {
  constexpr int BM = 128, BN = 128, BK = 32;
  __shared__ __align__(16) bf16 As[BM][BK];
  __shared__ __align__(16) bf16 Bs[BN][BK];
  const int tid = threadIdx.x;
  const int lane = tid & 63, wave = tid >> 6;
  const int bm = blockIdx.x * BM, bn = blockIdx.y * BN;
  const int wm = (wave >> 1) * 64, wn = (wave & 1) * 64;
  const int lrow = lane >> 2;       // 0..15
  const int lcol = (lane & 3) * 8;  // element offset (8 bf16 = 16B)

  f32x4 acc[4][4];
#pragma unroll
  for (int i = 0; i < 4; ++i)
#pragma unroll
    for (int j = 0; j < 4; ++j) acc[i][j] = (f32x4){0.f, 0.f, 0.f, 0.f};

  for (int k0 = 0; k0 < K; k0 += BK) {
#pragma unroll
    for (int r = 0; r < 2; ++r) {
      int arow = bm + wave * 32 + r * 16 + lrow;
      if (arow >= M) arow = M - 1;  // clamp: dup loads, masked at store
      gl_lds16(A + (size_t)arow * K + k0 + lcol, &As[wave * 32 + r * 16][0]);
      int brow = bn + wave * 32 + r * 16 + lrow;  // always < Nn (Nn%128==0)
      gl_lds16(BT + (size_t)brow * K + k0 + lcol, &Bs[wave * 32 + r * 16][0]);
    }
    __syncthreads();
    const int fr = lane & 15, kg = (lane >> 4) * 8;
    bf16x8 af[4], bfr[4];
#pragma unroll
    for (int i = 0; i < 4; ++i) {
      af[i] = *(const bf16x8*)&As[wm + i * 16 + fr][kg];
      bfr[i] = *(const bf16x8*)&Bs[wn + i * 16 + fr][kg];
    }
#pragma unroll
    for (int i = 0; i < 4; ++i)
#pragma unroll
      for (int j = 0; j < 4; ++j)
        acc[i][j] = __builtin_amdgcn_mfma_f32_16x16x32_bf16(af[i], bfr[j],
                                                            acc[i][j], 0, 0, 0);
    __syncthreads();
  }

  const int fr = lane & 15, rg = (lane >> 4) * 4;
#pragma unroll
  for (int j = 0; j < 4; ++j) {
    int col = bn + wn + j * 16 + fr;
    float bv = bias[col];
#pragma unroll
    for (int i = 0; i < 4; ++i) {
#pragma unroll
      for (int r = 0; r < 4; ++r) {
        int row = bm + wm + i * 16 + rg + r;
        if (row < M)
          C[(size_t)row * Nn + col] = (OutT)(acc[i][j][r] + bv);
      }
    }
  }
}

// --------------------------------------------- depthwise 3x3x3 pool + LN
// blockDim (64,4): one wave per output row. pwT: [27][96] transposed weights.
__global__ __launch_bounds__(256) void pool_ln(
    const bf16* __restrict__ qkv, const float* __restrict__ pwT,
    const float* __restrict__ g, const float* __restrict__ bt,
    bf16* __restrict__ outp, int which, int sHW, int oH, int oW, int Lout) {
  __shared__ float pwl[2592];  // 27 x 96 fp32, conflict-free lane-x reads
  const int tid = threadIdx.y * 64 + threadIdx.x;
  for (int i = tid; i < 2592; i += 256) pwl[i] = pwT[i];
  __syncthreads();

  const int bh = blockIdx.y;
  const int b = bh >> 3, h = bh & 7;
  const int orow = blockIdx.x * 4 + threadIdx.y;
  if (orow >= Lout) return;
  const int x = threadIdx.x;  // 0..63
  const bf16* base = qkv + (size_t)b * N_ * 2304 + which * 768 + h * 96;
  float v0 = 0.f, v1 = 0.f;
  if (orow == 0) {  // cls token: no pooling
    v0 = (float)base[x];
    if (x < 32) v1 = (float)base[x + 64];
  } else {
    int pos = orow - 1;
    int ot = pos / (oH * oW), r = pos % (oH * oW);
    int oh = r / oW, ow = r % oW;
    for (int kt = 0; kt < 3; ++kt) {
      int it = ot + kt - 1;
      if (it < 0 || it >= T0_) continue;
      for (int kh = 0; kh < 3; ++kh) {
        int ih = oh * sHW + kh - 1;
        if (ih < 0 || ih >= H0_) continue;
        for (int kw = 0; kw < 3; ++kw) {
          int iw = ow * sHW + kw - 1;
          if (iw < 0 || iw >= W0_) continue;
          int n = 1 + (it * H0_ + ih) * W0_ + iw;
          const bf16* ip = base + (size_t)n * 2304;
          int widx = (kt * 3 + kh) * 3 + kw;
          v0 += (float)ip[x] * pwl[widx * 96 + x];
          if (x < 32) v1 += (float)ip[x + 64] * pwl[widx * 96 + x + 64];
        }
      }
    }
  }
  float s = v0 + (x < 32 ? v1 : 0.f);
  float s2 = v0 * v0 + (x < 32 ? v1 * v1 : 0.f);
  for (int off = 32; off > 0; off >>= 1) {
    s += __shfl_down(s, off);
    s2 += __shfl_down(s2, off);
  }
  s = __shfl(s, 0);
  s2 = __shfl(s2, 0);
  float mean = s * (1.f / 96.f);
  float var = s2 * (1.f / 96.f) - mean * mean;
  float rstd = rsqrtf(var + 1e-5f);
  size_t ob = ((size_t)bh * Lout + orow) * 96;
  outp[ob + x] = __float2bfloat16((v0 - mean) * rstd * g[x] + bt[x]);
  if (x < 32)
    outp[ob + x + 64] =
        __float2bfloat16((v1 - mean) * rstd * g[x + 64] + bt[x + 64]);
}

// ------------------------------------------------- MFMA flash attention
// grid (25, 128): 64 q rows per block, one (b,h) per blockIdx.y. 256 thr.
__global__ __launch_bounds__(256) void attn_fused(
    const bf16* __restrict__ qp, const bf16* __restrict__ kp,
    const bf16* __restrict__ vp, const float* __restrict__ rph,
    const float* __restrict__ rpw, const float* __restrict__ rpt,
    bf16* __restrict__ aout) {
  __shared__ __align__(16) bf16 Qs[64][104];   // pad 96->104 (16B-aligned rows)
  __shared__ __align__(16) bf16 Ks[64][104];
  __shared__ __align__(16) bf16 Vt[96][72];    // V transposed [d][key]
  __shared__ __align__(16) bf16 Ps[4][16][72]; // per-wave P tile
  __shared__ float relb[64][24];               // t:0..7 h:8..14 w:16..22

  const int tid = threadIdx.x;
  const int wv = tid >> 6, lane = tid & 63;
  const int col = lane & 15, quad = lane >> 4;
  const int bh = blockIdx.y;
  const int b = bh >> 3, h = bh & 7;
  const int q0 = blockIdx.x * 64;
  const bf16* qb = qp + (size_t)bh * N_ * HD_;
  const bf16* kb = kp + (size_t)bh * LK_ * HD_;
  const bf16* vb = vp + (size_t)bh * LK_ * HD_;
  const float scale = 0.102062072615966f;  // 96^-0.5

  // ---- stage Q tile (64 x 96) ----
  for (int c = tid; c < 768; c += 256) {  // 768 chunks of 8 elems
    int row = c / 12, seg = c % 12;
    int p = q0 + row;
    if (p >= N_) p = N_ - 1;
    uint4 v = *(const uint4*)(qb + (size_t)p * HD_ + seg * 8);
    *(uint4*)&Qs[row][seg * 8] = v;
  }
  __syncthreads();

  // ---- rel-pos dot tables: 22 per q row ----
  for (int t = tid; t < 64 * 22; t += 256) {
    int qr = t / 22, j = t % 22;
    int p = q0 + qr;
    if (p >= 1 && p < N_) {
      int pos = p - 1;
      int qt = pos / 196, rr = pos % 196;
      int qh = rr / 14, qw = rr % 14;
      const float* tab;
      int slot;
      if (j < 8) { tab = rpt + (size_t)(qt - j + 7) * HD_; slot = j; }
      else if (j < 15) { int kh = j - 8; tab = rph + (size_t)(qh - 2 * kh + 12) * HD_; slot = j; }
      else { int kw = j - 15; tab = rpw + (size_t)(qw - 2 * kw + 12) * HD_; slot = 16 + kw; }
      float acc = 0.f;
      for (int d = 0; d < HD_; ++d) acc += (float)Qs[qr][d] * tab[d];
      relb[qr][slot] = acc;
    }
  }

  // ---- flash state (4 q rows per lane: row = wv*16 + quad*4 + r) ----
  float mrun[4] = {-1e30f, -1e30f, -1e30f, -1e30f};
  float lrun[4] = {0.f, 0.f, 0.f, 0.f};
  f32x4 oacc[6];
#pragma unroll
  for (int dt = 0; dt < 6; ++dt) oacc[dt] = (f32x4){0.f, 0.f, 0.f, 0.f};

  for (int kt_i = 0; kt_i < 7; ++kt_i) {
    const int kt0 = kt_i * 64;
    __syncthreads();  // prior reads of Ks/Vt done; relb visible (iter 0)
    // ---- stage K (64x96) and V^T (96x64) ----
    for (int c = tid; c < 768; c += 256) {
      int row = c / 12, seg = c % 12;
      int key = kt0 + row;
      if (key >= LK_) key = LK_ - 1;
      uint4 v = *(const uint4*)(kb + (size_t)key * HD_ + seg * 8);
      *(uint4*)&Ks[row][seg * 8] = v;
      union { uint4 u; bf16 e[8]; } tv;
      tv.u = *(const uint4*)(vb + (size_t)key * HD_ + seg * 8);
#pragma unroll
      for (int j = 0; j < 8; ++j) Vt[seg * 8 + j][row] = tv.e[j];
    }
    __syncthreads();

    // ---- S = Q K^T : wave wv computes rows [wv*16, wv*16+16) x 64 keys ----
    f32x4 sacc[4];
#pragma unroll
    for (int jt = 0; jt < 4; ++jt) sacc[jt] = (f32x4){0.f, 0.f, 0.f, 0.f};
#pragma unroll
    for (int ks_ = 0; ks_ < 3; ++ks_) {
      bf16x8 aq = *(const bf16x8*)&Qs[wv * 16 + col][ks_ * 32 + quad * 8];
#pragma unroll
      for (int jt = 0; jt < 4; ++jt) {
        bf16x8 bk = *(const bf16x8*)&Ks[jt * 16 + col][ks_ * 32 + quad * 8];
        sacc[jt] = __builtin_amdgcn_mfma_f32_16x16x32_bf16(aq, bk, sacc[jt], 0, 0, 0);
      }
    }

    // ---- scale + rel-pos bias + validity ----
    float sv[4][4];  // [jt][reg]
#pragma unroll
    for (int jt = 0; jt < 4; ++jt) {
      int kglob = kt0 + jt * 16 + col;
      bool kvalid = (kglob < LK_);
      int kbod = (kglob >= 1) ? kglob - 1 : 0;
      int kt_ = kbod / 49, krem = kbod % 49;
      int kh_ = krem / 7, kw_ = krem % 7;
#pragma unroll
      for (int r = 0; r < 4; ++r) {
        int qr = wv * 16 + quad * 4 + r;
        int p = q0 + qr;
        float s = sacc[jt][r] * scale;
        if (kvalid && kglob >= 1 && p >= 1 && p < N_)
          s += relb[qr][kt_] + relb[qr][8 + kh_] + relb[qr][16 + kw_];
        if (!kvalid) s = -1e30f;
        sv[jt][r] = s;
      }
    }

    // ---- online softmax (row spread over 16-lane cluster) ----
    float pexp[4][4];
#pragma unroll
    for (int r = 0; r < 4; ++r) {
      float pm = fmaxf(fmaxf(sv[0][r], sv[1][r]), fmaxf(sv[2][r], sv[3][r]));
#pragma unroll
      for (int mk = 1; mk < 16; mk <<= 1) pm = fmaxf(pm, __shfl_xor(pm, mk));
      float mn = fmaxf(mrun[r], pm);
      float alpha = __expf(mrun[r] - mn);
      mrun[r] = mn;
      float rs = 0.f;
#pragma unroll
      for (int jt = 0; jt < 4; ++jt) {
        float e = __expf(sv[jt][r] - mn);
        pexp[jt][r] = e;
        rs += e;
      }
#pragma unroll
      for (int mk = 1; mk < 16; mk <<= 1) rs += __shfl_xor(rs, mk);
      lrun[r] = lrun[r] * alpha + rs;
#pragma unroll
      for (int dt = 0; dt < 6; ++dt) {
        oacc[dt][r] *= alpha;
      }
    }

    // ---- P (C-layout) -> LDS -> A-layout ----
#pragma unroll
    for (int jt = 0; jt < 4; ++jt)
#pragma unroll
      for (int r = 0; r < 4; ++r)
        Ps[wv][quad * 4 + r][jt * 16 + col] = __float2bfloat16(pexp[jt][r]);
    // wave-private LDS region: compiler's lgkmcnt wait orders write->read

    // ---- O += P V ----
#pragma unroll
    for (int ks_ = 0; ks_ < 2; ++ks_) {
      bf16x8 ap = *(const bf16x8*)&Ps[wv][col][ks_ * 32 + quad * 8];
#pragma unroll
      for (int dt = 0; dt < 6; ++dt) {
        bf16x8 bv = *(const bf16x8*)&Vt[dt * 16 + col][ks_ * 32 + quad * 8];
        oacc[dt] = __builtin_amdgcn_mfma_f32_16x16x32_bf16(ap, bv, oacc[dt], 0, 0, 0);
      }
    }
  }

  // ---- epilogue: O/l + residual q, store bf16 ----
#pragma unroll
  for (int r = 0; r < 4; ++r) {
    int qr = wv * 16 + quad * 4 + r;
    int p = q0 + qr;
    if (p >= N_) continue;
    float inv = 1.f / lrun[r];
#pragma unroll
    for (int dt = 0; dt < 6; ++dt) {
      int d = dt * 16 + col;
      float val = oacc[dt][r] * inv;
      if (p >= 1) val += (float)Qs[qr][d];
      aout[((size_t)b * N_ + p) * DIM_ + h * HD_ + d] = __float2bfloat16(val);
    }
  }
}

// ------------------------------------------------------------------- launch
extern "C" void kernel_launch(void* const* d_in, const int* in_sizes, int n_in,
                              void* d_out, int out_size, void* d_ws,
                              size_t ws_size, hipStream_t stream) {
  (void)in_sizes; (void)n_in; (void)out_size; (void)ws_size;
  const float* x      = (const float*)d_in[0];
  const float* qkv_w  = (const float*)d_in[1];
  const float* qkv_b  = (const float*)d_in[2];
  const float* pool_q = (const float*)d_in[3];
  const float* pool_k = (const float*)d_in[4];
  const float* pool_v = (const float*)d_in[5];
  const float* ln_q_g = (const float*)d_in[6];
  const float* ln_q_b = (const float*)d_in[7];
  const float* ln_k_g = (const float*)d_in[8];
  const float* ln_k_b = (const float*)d_in[9];
  const float* ln_v_g = (const float*)d_in[10];
  const float* ln_v_b = (const float*)d_in[11];
  const float* rph    = (const float*)d_in[12];
  const float* rpw    = (const float*)d_in[13];
  const float* rpt    = (const float*)d_in[14];
  const float* proj_w = (const float*)d_in[15];
  const float* proj_b = (const float*)d_in[16];

  char* ws = (char*)d_ws;
  bf16* wt_qkv  = (bf16*)(ws);                  // 2304x768 bf16   (3.54 MB)
  bf16* wt_proj = (bf16*)(ws + 3538944);        // 768x768 bf16    (1.18 MB)
  bf16* xb      = (bf16*)(ws + 4718592);        // 25104x768 bf16  (38.6 MB)
  bf16* aout    = xb;                           // reuse: xb dead after gemm#1
  bf16* qkv     = (bf16*)(ws + 43278336);       // 25104x2304 bf16 (115.7 MB)
  bf16* qpoolb  = (bf16*)(ws + 158957568);      // 128x1569x96 bf16 (38.6 MB)
  bf16* kpoolb  = (bf16*)(ws + 197517312);      // 128x393x96 bf16  (9.7 MB)
  bf16* vpoolb  = (bf16*)(ws + 207175680);      // 128x393x96 bf16  (9.7 MB)
  float* pwT    = (float*)(ws + 216834048);     // 3x27x96 fp32     (31 KB)
  float* outp   = (float*)d_out;                // fp32 output per reference

  int n4 = (B_ * N_ * DIM_) / 4;
  cvt_f32_bf16<<<(n4 + 255) / 256, 256, 0, stream>>>(x, xb, n4);
  transpose_f32_bf16<<<dim3(72, 24), dim3(32, 8), 0, stream>>>(qkv_w, wt_qkv, 768, 2304);
  transpose_f32_bf16<<<dim3(24, 24), dim3(32, 8), 0, stream>>>(proj_w, wt_proj, 768, 768);
  prep_pw<<<11, 256, 0, stream>>>(pool_q, pool_k, pool_v, pwT);

  gemm_bt<bf16><<<dim3(197, 18), 256, 0, stream>>>(xb, wt_qkv, qkv_b, qkv,
                                                   B_ * N_, 3 * DIM_, DIM_);

  dim3 pb(64, 4);
  pool_ln<<<dim3(393, 128), pb, 0, stream>>>(qkv, pwT, ln_q_g, ln_q_b, qpoolb,
                                             0, 1, 14, 14, N_);
  pool_ln<<<dim3(99, 128), pb, 0, stream>>>(qkv, pwT + 2592, ln_k_g, ln_k_b,
                                            kpoolb, 1, 2, 7, 7, LK_);
  pool_ln<<<dim3(99, 128), pb, 0, stream>>>(qkv, pwT + 5184, ln_v_g, ln_v_b,
                                            vpoolb, 2, 2, 7, 7, LK_);

  attn_fused<<<dim3(25, 128), 256, 0, stream>>>(qpoolb, kpoolb, vpoolb, rph,
                                                rpw, rpt, aout);

  gemm_bt<float><<<dim3(197, 6), 256, 0, stream>>>(aout, wt_proj, proj_b, outp,
                                                   B_ * N_, DIM_, DIM_);
}